// Round 4
// baseline (217.918 us; speedup 1.0000x reference)
//
#include <hip/hip_runtime.h>
#include <hip/hip_bf16.h>

// Problem constants (match reference)
#define PB 8          // batches
#define PS 2048       // sequence length
#define PN 4096       // spans per batch
#define PD 256        // feature dim
#define CHUNK 64
#define NCHUNK (PS / CHUNK)   // 32
// MAX_W = 16: starts in [0, S-16), width in [0,15] -> end+1 <= 2047 < PS,
// so P needs only PS rows (P[b,s,:] = sum of rows [0,s), exclusive).

// ---------------------------------------------------------------------------
// K_A: fused chunk-sum + cross-chunk scan + P-row write, in ONE kernel.
// Grid = PB*NCHUNK = 256 blocks (one per (batch, chunk)) -> all co-resident
// on 256 CUs, so flag spin-waiting cannot deadlock. 256 threads = one column
// each of D=256.
//
// Flag protocol: harness re-poisons d_ws to 0xAA before EVERY launch, so
// flags start at 0xAAAAAAAA != 1. Publisher: store csum, __threadfence,
// __syncthreads, lane0 release-stores flag=1. Consumer: acquire-load spins
// until flag==1, then reads csum (acquire invalidates L1).
__global__ __launch_bounds__(256) void k_buildP(const float* __restrict__ seq,
                                                float* __restrict__ P,
                                                float* __restrict__ csum,
                                                int*   __restrict__ flags) {
    const int b = blockIdx.x & 7;          // batch == XCD (round-robin dispatch)
    const int c = blockIdx.x >> 3;         // chunk 0..31
    const int d = threadIdx.x;             // column 0..255

    const size_t rowbase = ((size_t)b * PS + (size_t)c * CHUNK) * PD + d;
    const float* ps = seq + rowbase;
    float*       pp = P   + rowbase;

    // Register-cache the 64 rows of this (batch,chunk,column).
    float v[CHUNK];
    #pragma unroll
    for (int i = 0; i < CHUNK; ++i) v[i] = ps[(size_t)i * PD];

    float s = 0.f;
    #pragma unroll
    for (int i = 0; i < CHUNK; ++i) s += v[i];

    csum[(((size_t)b << 5) + c) * PD + d] = s;
    __threadfence();                       // make csum visible device-wide
    __syncthreads();                       // all 256 columns' stores done
    if (d == 0)
        __hip_atomic_store(&flags[(b << 5) + c], 1,
                           __ATOMIC_RELEASE, __HIP_MEMORY_SCOPE_AGENT);

    // Accumulate offset = sum of predecessor chunk sums (c <= 31 iterations).
    float off = 0.f;
    for (int cc = 0; cc < c; ++cc) {
        while (__hip_atomic_load(&flags[(b << 5) + cc],
                                 __ATOMIC_ACQUIRE, __HIP_MEMORY_SCOPE_AGENT) != 1) {
            __builtin_amdgcn_s_sleep(1);
        }
        off += csum[(((size_t)b << 5) + cc) * PD + d];
    }

    // Stream P rows: P[row i] = running exclusive prefix.
    float run = off;
    #pragma unroll
    for (int i = 0; i < CHUNK; ++i) {
        pp[(size_t)i * PD] = run;
        run += v[i];
    }
}

// ---------------------------------------------------------------------------
// K_B: gather. One wave per span; lane owns float4 [4*lane, 4*lane+4).
// out = (P[end+1] - P[start]) / (width+1). 2 KiB read + 1 KiB write per span.
__global__ __launch_bounds__(256) void k_gather(const float* __restrict__ P,
                                               const int*   __restrict__ spans,
                                               float*       __restrict__ out) {
    const int b       = blockIdx.x & 7;            // batch == XCD
    const int blk     = blockIdx.x >> 3;
    const int span_ib = (blk << 2) | (threadIdx.x >> 6);
    const int span    = (b << 12) | span_ib;
    const int lane    = threadIdx.x & 63;

    const int2 se = ((const int2*)spans)[span];    // x=start, y=end (inclusive)
    const float inv = 1.0f / (float)(se.y - se.x + 1);

    const float* Pb = P + ((size_t)b * PS) * PD + (lane << 2);
    const float4 p0 = *(const float4*)(Pb + (size_t)se.x       * PD);
    const float4 p1 = *(const float4*)(Pb + (size_t)(se.y + 1) * PD);

    float4 r;
    r.x = (p1.x - p0.x) * inv;
    r.y = (p1.y - p0.y) * inv;
    r.z = (p1.z - p0.z) * inv;
    r.w = (p1.w - p0.w) * inv;

    *(float4*)(out + (size_t)span * PD + (lane << 2)) = r;
}

extern "C" void kernel_launch(void* const* d_in, const int* in_sizes, int n_in,
                              void* d_out, int out_size, void* d_ws, size_t ws_size,
                              hipStream_t stream) {
    const float* seq   = (const float*)d_in[0];   // (B,S,D) f32
    const int*   spans = (const int*)d_in[1];     // (B,N,2) i32
    float*       out   = (float*)d_out;           // (B,N,D) f32

    // Workspace layout (re-poisoned 0xAA before every launch — flags rely on it):
    //   P     : PB*PS*PD floats      (16 MiB)
    //   csum  : PB*NCHUNK*PD floats  (256 KiB)
    //   flags : PB*NCHUNK ints       (1 KiB)   poison 0xAAAAAAAA != 1 == "not ready"
    float* P     = (float*)d_ws;
    float* csum  = P    + (size_t)PB * PS * PD;
    int*   flags = (int*)(csum + (size_t)PB * NCHUNK * PD);

    k_buildP<<<dim3(PB * NCHUNK), dim3(256), 0, stream>>>(seq, P, csum, flags);
    k_gather<<<dim3(PB * PN / 4), dim3(256), 0, stream>>>(P, spans, out);
}

// Round 5
// 86.846 us; speedup vs baseline: 2.5092x; 2.5092x over previous
//
#include <hip/hip_runtime.h>
#include <hip/hip_bf16.h>

// Problem constants (match reference)
#define PB 8          // batches
#define PS 2048       // sequence length
#define PN 4096       // spans per batch
#define PD 256        // feature dim
// MAX_W = 16: start in [0, S-16), width in [0,15] -> rows start..start+15
// are ALWAYS in-bounds, and the span covers rows start..start+width.

typedef float vf4 __attribute__((ext_vector_type(4)));

// One wave (64 lanes) per span; lane owns float4 [4*lane, 4*lane+4) of D=256.
// Block = 256 threads = 4 spans; grid = 8192 blocks.
// blockIdx & 7 = batch: blocks go round-robin to XCDs, so each XCD gathers
// from one batch's 2 MiB seq slice -> L2-resident.
__global__ __launch_bounds__(256) void span_mean_kernel(
    const float* __restrict__ seq,     // (B, S, D) f32
    const int*   __restrict__ spans,   // (B, N, 2) i32: start, end
    float*       __restrict__ out)     // (B, N, D) f32
{
    const int b       = blockIdx.x & 7;            // batch == XCD
    const int blk     = blockIdx.x >> 3;
    const int span_ib = (blk << 2) | (threadIdx.x >> 6);
    const int span    = (b << 12) | span_ib;
    const int lane    = threadIdx.x & 63;

    const int2 se    = ((const int2*)spans)[span]; // same addr for all 64 lanes
    // Wave-uniform by construction -> force into SGPRs: scalar branches,
    // scalar base address, zero VALU spent on control.
    const int  start = __builtin_amdgcn_readfirstlane(se.x);
    const int  width = __builtin_amdgcn_readfirstlane(se.y) - start;  // 0..15

    const float inv = 1.0f / (float)(width + 1);

    const float* base = seq + (((size_t)b * PS + start) * PD) + (lane << 2);
#define LD(w) (*(const vf4*)(base + (w) * PD))

    // Row 0 always belongs to the span (width >= 0): issue it first (oldest).
    vf4 A = LD(0);

    // Issue rows width..1 back-to-back with NO intervening waits: descending
    // fall-through switch = width loads in flight on top of A's load.
    vf4 v1, v2, v3, v4, v5, v6, v7, v8, v9, v10, v11, v12, v13, v14, v15;
    switch (width) {
        case 15: v15 = LD(15); [[fallthrough]];
        case 14: v14 = LD(14); [[fallthrough]];
        case 13: v13 = LD(13); [[fallthrough]];
        case 12: v12 = LD(12); [[fallthrough]];
        case 11: v11 = LD(11); [[fallthrough]];
        case 10: v10 = LD(10); [[fallthrough]];
        case 9:  v9  = LD(9);  [[fallthrough]];
        case 8:  v8  = LD(8);  [[fallthrough]];
        case 7:  v7  = LD(7);  [[fallthrough]];
        case 6:  v6  = LD(6);  [[fallthrough]];
        case 5:  v5  = LD(5);  [[fallthrough]];
        case 4:  v4  = LD(4);  [[fallthrough]];
        case 3:  v3  = LD(3);  [[fallthrough]];
        case 2:  v2  = LD(2);  [[fallthrough]];
        case 1:  v1  = LD(1);  break;
        default: break;
    }

    // Sum into 4 rotating accumulators (ILP in the add tree). Scalar-branch
    // ladder, ascending — structurally distinct from the switch so the
    // compiler doesn't re-fuse load+add per row (which would serialize).
    vf4 Bq = {0.f, 0.f, 0.f, 0.f};
    vf4 Cq = {0.f, 0.f, 0.f, 0.f};
    vf4 Dq = {0.f, 0.f, 0.f, 0.f};
    if (width >= 1)  Bq += v1;
    if (width >= 2)  Cq += v2;
    if (width >= 3)  Dq += v3;
    if (width >= 4)  A  += v4;
    if (width >= 5)  Bq += v5;
    if (width >= 6)  Cq += v6;
    if (width >= 7)  Dq += v7;
    if (width >= 8)  A  += v8;
    if (width >= 9)  Bq += v9;
    if (width >= 10) Cq += v10;
    if (width >= 11) Dq += v11;
    if (width >= 12) A  += v12;
    if (width >= 13) Bq += v13;
    if (width >= 14) Cq += v14;
    if (width >= 15) Dq += v15;

    vf4 r = ((A + Bq) + (Cq + Dq)) * inv;

    // out is written once and never read: nontemporal store keeps the 32 MiB
    // stream from evicting the L2-resident seq slice.
    __builtin_nontemporal_store(r, (vf4*)(out + (size_t)span * PD + (lane << 2)));
#undef LD
}

extern "C" void kernel_launch(void* const* d_in, const int* in_sizes, int n_in,
                              void* d_out, int out_size, void* d_ws, size_t ws_size,
                              hipStream_t stream) {
    const float* seq   = (const float*)d_in[0];   // (B,S,D) f32
    const int*   spans = (const int*)d_in[1];     // (B,N,2) i32
    float*       out   = (float*)d_out;           // (B,N,D) f32

    const int n_spans = PB * PN;                  // 32768
    dim3 grid(n_spans / 4);                       // 4 spans per 256-thread block
    dim3 block(256);
    span_mean_kernel<<<grid, block, 0, stream>>>(seq, spans, out);
}

// Round 6
// 82.764 us; speedup vs baseline: 2.6330x; 1.0493x over previous
//
#include <hip/hip_runtime.h>
#include <hip/hip_bf16.h>

// Problem constants (match reference)
#define PB 8          // batches
#define PS 2048       // sequence length
#define PN 4096       // spans per batch
#define PD 256        // feature dim
// MAX_W = 16: start in [0, S-16), width in [0,15] -> rows start..start+15
// are ALWAYS in-bounds; the span covers rows start..start+width (n = width+1).

typedef float vf4 __attribute__((ext_vector_type(4)));

// One wave (64 lanes) per span; lane owns float4 [4*lane, 4*lane+4) of D=256.
// Block = 256 threads = 4 spans; grid = 8192 blocks.
// blockIdx & 7 = batch: blocks round-robin across the 8 XCDs, so each XCD
// gathers from one batch's 2 MiB seq slice -> L2-resident.
__global__ __launch_bounds__(256) void span_mean_kernel(
    const float* __restrict__ seq,     // (B, S, D) f32
    const int*   __restrict__ spans,   // (B, N, 2) i32: start, end
    float*       __restrict__ out)     // (B, N, D) f32
{
    const int b       = blockIdx.x & 7;            // batch == XCD
    const int blk     = blockIdx.x >> 3;
    const int span_ib = (blk << 2) | (threadIdx.x >> 6);
    const int span    = (b << 12) | span_ib;
    const int lane    = threadIdx.x & 63;

    const int2 se    = ((const int2*)spans)[span]; // same addr for all 64 lanes
    // Wave-uniform -> SGPRs: all row-presence branches are scalar (s_cbranch),
    // no jump table (R5's switch regressed: indirect branch + reg pressure).
    const int  start = __builtin_amdgcn_readfirstlane(se.x);
    const int  n     = __builtin_amdgcn_readfirstlane(se.y) - start + 1; // 1..16

    const float inv = 1.0f / (float)n;

    const float* base = seq + (((size_t)b * PS + start) * PD) + (lane << 2);
#define LD(w) (*(const vf4*)(base + (w) * PD))
    const vf4 Z = {0.f, 0.f, 0.f, 0.f};

    // Row 0 always present (n >= 1). Rows 1..15: load-or-zero under a scalar
    // branch. The adds below are UNCONDITIONAL, so the compiler cannot merge
    // a row's load with its add (which would serialize on vmcnt per row) —
    // all taken loads issue back-to-back, then one batched drain.
    const vf4 v0  = LD(0);
    const vf4 v1  = (n >  1) ? LD(1)  : Z;
    const vf4 v2  = (n >  2) ? LD(2)  : Z;
    const vf4 v3  = (n >  3) ? LD(3)  : Z;
    const vf4 v4  = (n >  4) ? LD(4)  : Z;
    const vf4 v5  = (n >  5) ? LD(5)  : Z;
    const vf4 v6  = (n >  6) ? LD(6)  : Z;
    const vf4 v7  = (n >  7) ? LD(7)  : Z;
    const vf4 v8  = (n >  8) ? LD(8)  : Z;
    const vf4 v9  = (n >  9) ? LD(9)  : Z;
    const vf4 v10 = (n > 10) ? LD(10) : Z;
    const vf4 v11 = (n > 11) ? LD(11) : Z;
    const vf4 v12 = (n > 12) ? LD(12) : Z;
    const vf4 v13 = (n > 13) ? LD(13) : Z;
    const vf4 v14 = (n > 14) ? LD(14) : Z;
    const vf4 v15 = (n > 15) ? LD(15) : Z;

    // Unconditional 4-way add tree (ILP), then one multiply by 1/n.
    const vf4 s0 = (v0  + v4)  + (v8  + v12);
    const vf4 s1 = (v1  + v5)  + (v9  + v13);
    const vf4 s2 = (v2  + v6)  + (v10 + v14);
    const vf4 s3 = (v3  + v7)  + (v11 + v15);
    const vf4 r  = ((s0 + s1) + (s2 + s3)) * inv;

    *(vf4*)(out + (size_t)span * PD + (lane << 2)) = r;
#undef LD
}

extern "C" void kernel_launch(void* const* d_in, const int* in_sizes, int n_in,
                              void* d_out, int out_size, void* d_ws, size_t ws_size,
                              hipStream_t stream) {
    const float* seq   = (const float*)d_in[0];   // (B,S,D) f32
    const int*   spans = (const int*)d_in[1];     // (B,N,2) i32
    float*       out   = (float*)d_out;           // (B,N,D) f32

    const int n_spans = PB * PN;                  // 32768
    dim3 grid(n_spans / 4);                       // 4 spans per 256-thread block
    dim3 block(256);
    span_mean_kernel<<<grid, block, 0, stream>>>(seq, spans, out);
}